// Round 3
// baseline (2570.764 us; speedup 1.0000x reference)
//
#include <hip/hip_runtime.h>
#include <math.h>

#define NN    8
#define CC    128
#define NA    180
#define NR    180
#define HH    160
#define WW    160
#define NPIX  (HH * WW)        // 25600
#define SLICE (NA * NR)        // 32400 floats per (n,c)
#define CHG   8                // channels interleaved per block (bf16 x8 = 16B per (a,rho))
#define NCG   (CC / CHG)       // 16
#define PXG   2560             // pixels per block
#define NPG   (NPIX / PXG)     // 10
#define TPB   640              // 10 waves
#define KPT   4                // pixels per thread (u8 idx packed in one uint)
#define ACH   20               // angles per LDS chunk
#define NCHUNK (NA / ACH)      // 9

// ---------- init 1: f64 trig tables (bit-match numpy) ----------
__global__ void iht_tabs(double* tabs) {
    int a = threadIdx.x;
    if (a < NA) {
        const double irho = 227.0 / 180.0;   // (int(sqrt(160^2+160^2))+1)/NUMRHO
        double th = (double)a * (M_PI / 180.0);
        tabs[a]      = cos(th) / irho;
        tabs[a + NA] = sin(th) / irho;
    }
}

// ---------- init 2: u8 rho table in PERMUTED layout [a][g][w][lane][k] ----------
// byte (a, g, w, lane, k)  <->  pixel = g*2560 + w*256 + k*64 + lane
__global__ void iht_ridx(const double* __restrict__ tabs,
                         unsigned char* __restrict__ ridx) {
    int id = blockIdx.x * blockDim.x + threadIdx.x;
    if (id >= NA * NPIX) return;
    int a    = id / NPIX;
    int rest = id - a * NPIX;
    int g    = rest / PXG;
    int r1   = rest - g * PXG;
    int w    = r1 >> 8;          // 256 bytes per wave row
    int r2   = r1 & 255;
    int lane = r2 >> 2;
    int k    = r2 & 3;
    int pixel = g * PXG + w * 256 + k * 64 + lane;
    int y = pixel / WW;
    int x = pixel - y * WW;
    double v = (double)(x - WW / 2) * tabs[a] + (double)(y - HH / 2) * tabs[a + NA];
    int r = __double2int_rn(v) + NR / 2;     // round-half-even == np.round
    r = min(max(r, 0), NR - 1);
    ridx[id] = (unsigned char)r;
}

// bf16 round-nearest-even pack of two floats
__device__ __forceinline__ unsigned int bf2pack(float f0, float f1) {
    unsigned int u0 = __float_as_uint(f0);
    unsigned int u1 = __float_as_uint(f1);
    u0 = (u0 + 0x7FFFu + ((u0 >> 16) & 1u)) >> 16;
    u1 = (u1 + 0x7FFFu + ((u1 >> 16) & 1u)) & 0xFFFF0000u;
    return u0 | u1;
}
__device__ __forceinline__ float bflo(unsigned int u) { return __uint_as_float(u << 16); }
__device__ __forceinline__ float bfhi(unsigned int u) { return __uint_as_float(u & 0xFFFF0000u); }

// ---------- main: 8-channel bf16-interleaved LDS gather via ds_read_b128 ----------
__global__ __launch_bounds__(TPB) void iht_main(const float* __restrict__ hough,
                                                const unsigned char* __restrict__ ridx,
                                                float* __restrict__ out) {
    __shared__ uint4 lds4[ACH * NR];         // 57.6 KB: [al][rho] -> 8 bf16 channels
    const int tid  = threadIdx.x;
    const int lane = tid & 63;
    const int w    = tid >> 6;               // wave id 0..9
    const int b    = blockIdx.x;
    const int n    = b / (NCG * NPG);
    const int rb   = b - n * (NCG * NPG);
    const int cg   = rb / NPG;
    const int g    = rb - cg * NPG;

    const float* __restrict__ src = hough + ((size_t)n * CC + (size_t)cg * CHG) * SLICE;

    float acc[KPT][CHG];
#pragma unroll
    for (int k = 0; k < KPT; ++k)
#pragma unroll
        for (int c = 0; c < CHG; ++c) acc[k][c] = 0.f;

    for (int chunk = 0; chunk < NCHUNK; ++chunk) {
        const int a0 = chunk * ACH;

        // ---- issue this chunk's index loads early (independent of LDS) ----
        uint idxr[ACH];
        {
            const uint* __restrict__ ip =
                (const uint*)ridx + (size_t)a0 * (NPIX / 4) + g * (PXG / 4) + w * 64 + lane;
#pragma unroll
            for (int al = 0; al < ACH; ++al)
                idxr[al] = ip[al * (NPIX / 4)];
        }

        __syncthreads();   // previous chunk's gathers done before overwrite
        // ---- stage 8 channels x 20 angles x 180 rho as packed bf16 ----
#pragma unroll
        for (int it = 0; it < (ACH * NR + TPB - 1) / TPB; ++it) {
            int idx = it * TPB + tid;
            if (idx < ACH * NR) {
                int al  = idx / NR;
                int rho = idx - al * NR;
                size_t go = (size_t)(a0 + al) * NR + rho;
                float f0 = src[go];
                float f1 = src[go + (size_t)1 * SLICE];
                float f2 = src[go + (size_t)2 * SLICE];
                float f3 = src[go + (size_t)3 * SLICE];
                float f4 = src[go + (size_t)4 * SLICE];
                float f5 = src[go + (size_t)5 * SLICE];
                float f6 = src[go + (size_t)6 * SLICE];
                float f7 = src[go + (size_t)7 * SLICE];
                uint4 p;
                p.x = bf2pack(f0, f1);
                p.y = bf2pack(f2, f3);
                p.z = bf2pack(f4, f5);
                p.w = bf2pack(f6, f7);
                lds4[idx] = p;               // lanes contiguous -> conflict-free b128 writes
            }
        }
        __syncthreads();

        // ---- gather: per angle, 4 pixels/thread, one ds_read_b128 = 8 channels ----
#pragma unroll
        for (int al = 0; al < ACH; ++al) {
            uint wv = idxr[al];
#pragma unroll
            for (int k = 0; k < KPT; ++k) {
                uint r = (wv >> (8 * k)) & 0xFFu;
                uint4 v = lds4[al * NR + (int)r];   // offset al*2880 folds into imm
                acc[k][0] += bflo(v.x); acc[k][1] += bfhi(v.x);
                acc[k][2] += bflo(v.y); acc[k][3] += bfhi(v.y);
                acc[k][4] += bflo(v.z); acc[k][5] += bfhi(v.z);
                acc[k][6] += bflo(v.w); acc[k][7] += bfhi(v.w);
            }
        }
    }

    // ---- store: 32 coalesced scalar f32 stores ----
    float* __restrict__ dst = out + ((size_t)n * CC + (size_t)cg * CHG) * NPIX
                                  + g * PXG + w * 256 + lane;
#pragma unroll
    for (int c = 0; c < CHG; ++c)
#pragma unroll
        for (int k = 0; k < KPT; ++k)
            dst[(size_t)c * NPIX + k * 64] = acc[k][c];
}

extern "C" void kernel_launch(void* const* d_in, const int* in_sizes, int n_in,
                              void* d_out, int out_size, void* d_ws, size_t ws_size,
                              hipStream_t stream) {
    const float* hough = (const float*)d_in[0];
    float* out = (float*)d_out;

    unsigned char* ridx = (unsigned char*)d_ws;                     // 4,608,000 B
    double* tabs = (double*)((char*)d_ws + (size_t)NA * NPIX);      // 2,880 B, 8B-aligned

    iht_tabs<<<1, 192, 0, stream>>>(tabs);
    iht_ridx<<<(NA * NPIX + 255) / 256, 256, 0, stream>>>(tabs, ridx);
    iht_main<<<NN * NCG * NPG, TPB, 0, stream>>>(hough, ridx, out);
}

// Round 7
// 597.839 us; speedup vs baseline: 4.3001x; 4.3001x over previous
//
#include <hip/hip_runtime.h>
#include <math.h>

#define NN    8
#define CC    128
#define NA    180
#define NR    180
#define HH    160
#define WW    160
#define NPIX  (HH * WW)        // 25600
#define SLICE (NA * NR)        // 32400 floats per (n,c)
#define CHG   4                // channels interleaved per block (f32 x4 = 16B per (a,rho))
#define NCG   (CC / CHG)       // 32
#define PXG   2560             // pixels per block
#define NPG   (NPIX / PXG)     // 10
#define TPB   640              // 10 waves
#define KPT   4                // pixels per thread (u8 idx packed in one uint)
#define ACH   20               // angles per LDS chunk
#define NCHUNK (NA / ACH)      // 9

// ---------- init 1: f64 trig tables (bit-match numpy) ----------
__global__ void iht_tabs(double* tabs) {
    int a = threadIdx.x;
    if (a < NA) {
        const double irho = 227.0 / 180.0;   // (int(sqrt(160^2+160^2))+1)/NUMRHO
        double th = (double)a * (M_PI / 180.0);
        tabs[a]      = cos(th) / irho;
        tabs[a + NA] = sin(th) / irho;
    }
}

// ---------- init 2: u8 rho table in PERMUTED layout [a][g][w][lane][k] ----------
// byte (a, g, w, lane, k)  <->  pixel = g*2560 + w*256 + k*64 + lane
__global__ void iht_ridx(const double* __restrict__ tabs,
                         unsigned char* __restrict__ ridx) {
    int id = blockIdx.x * blockDim.x + threadIdx.x;
    if (id >= NA * NPIX) return;
    int a    = id / NPIX;
    int rest = id - a * NPIX;
    int g    = rest / PXG;
    int r1   = rest - g * PXG;
    int w    = r1 >> 8;          // 256 bytes per wave row
    int r2   = r1 & 255;
    int lane = r2 >> 2;
    int k    = r2 & 3;
    int pixel = g * PXG + w * 256 + k * 64 + lane;
    int y = pixel / WW;
    int x = pixel - y * WW;
    double v = (double)(x - WW / 2) * tabs[a] + (double)(y - HH / 2) * tabs[a + NA];
    int r = __double2int_rn(v) + NR / 2;     // round-half-even == np.round
    r = min(max(r, 0), NR - 1);
    ridx[id] = (unsigned char)r;
}

// ---------- main: 4-channel f32-interleaved LDS gather via ds_read_b128 ----------
__global__ __launch_bounds__(TPB) void iht_main(const float* __restrict__ hough,
                                                const unsigned char* __restrict__ ridx,
                                                float* __restrict__ out) {
    __shared__ float4 ldsf[ACH * NR];        // 57.6 KB: [al][rho] -> 4 f32 channels
    const int tid  = threadIdx.x;
    const int lane = tid & 63;
    const int w    = tid >> 6;               // wave id 0..9
    const int b    = blockIdx.x;             // ((n*NPG + g)*NCG + cg): cg fastest -> XCDs share (n,g)
    const int cg   = b & (NCG - 1);
    const int q    = b >> 5;
    const int g    = q % NPG;
    const int n    = q / NPG;

    const float* __restrict__ src = hough + ((size_t)n * CC + (size_t)cg * CHG) * SLICE;

    float acc[KPT][CHG];
#pragma unroll
    for (int k = 0; k < KPT; ++k)
#pragma unroll
        for (int c = 0; c < CHG; ++c) acc[k][c] = 0.f;

    // per-thread index pointer (permuted table: one uint = 4 pixels' rho for angle a)
    const uint* __restrict__ ipbase =
        (const uint*)ridx + (size_t)g * (PXG / 4) + w * 64 + lane;

    for (int chunk = 0; chunk < NCHUNK; ++chunk) {
        const int a0 = chunk * ACH;

        __syncthreads();   // previous chunk's gathers done before overwrite
        // ---- stage 4 channels x 20 angles x 180 rho as float4 ----
#pragma unroll
        for (int it = 0; it < (ACH * NR + TPB - 1) / TPB; ++it) {
            int idx = it * TPB + tid;
            if (idx < ACH * NR) {
                int al  = idx / NR;
                int rho = idx - al * NR;
                size_t go = (size_t)(a0 + al) * NR + rho;
                float4 p;
                p.x = src[go];
                p.y = src[go + (size_t)1 * SLICE];
                p.z = src[go + (size_t)2 * SLICE];
                p.w = src[go + (size_t)3 * SLICE];
                ldsf[idx] = p;               // lanes contiguous -> conflict-free b128 writes
            }
        }
        __syncthreads();

        // ---- gather: per angle, 4 pixels/thread, one ds_read_b128 = 4 channels ----
        const uint* __restrict__ ip = ipbase + (size_t)a0 * (NPIX / 4);
#pragma unroll 5
        for (int al = 0; al < ACH; ++al) {
            uint wv = ip[al * (NPIX / 4)];   // coalesced 256B per wave, L2-resident
#pragma unroll
            for (int k = 0; k < KPT; ++k) {
                uint r = (wv >> (8 * k)) & 0xFFu;
                float4 v = ldsf[al * NR + (int)r];
                acc[k][0] += v.x;
                acc[k][1] += v.y;
                acc[k][2] += v.z;
                acc[k][3] += v.w;
            }
        }
    }

    // ---- store: 16 coalesced scalar f32 stores (256B per wave each) ----
    float* __restrict__ dst = out + ((size_t)n * CC + (size_t)cg * CHG) * NPIX
                                  + g * PXG + w * 256 + lane;
#pragma unroll
    for (int c = 0; c < CHG; ++c)
#pragma unroll
        for (int k = 0; k < KPT; ++k)
            dst[(size_t)c * NPIX + k * 64] = acc[k][c];
}

extern "C" void kernel_launch(void* const* d_in, const int* in_sizes, int n_in,
                              void* d_out, int out_size, void* d_ws, size_t ws_size,
                              hipStream_t stream) {
    const float* hough = (const float*)d_in[0];
    float* out = (float*)d_out;

    unsigned char* ridx = (unsigned char*)d_ws;                     // 4,608,000 B
    double* tabs = (double*)((char*)d_ws + (size_t)NA * NPIX);      // 2,880 B, 8B-aligned

    iht_tabs<<<1, 192, 0, stream>>>(tabs);
    iht_ridx<<<(NA * NPIX + 255) / 256, 256, 0, stream>>>(tabs, ridx);
    iht_main<<<NN * NCG * NPG, TPB, 0, stream>>>(hough, ridx, out);
}